// Round 1
// baseline (645.685 us; speedup 1.0000x reference)
//
#include <hip/hip_runtime.h>
#include <cfloat>

typedef _Float16 half8 __attribute__((ext_vector_type(8)));
typedef float    f32x4 __attribute__((ext_vector_type(4)));

#define N_ROWS 65536
#define DIM    256
#define KCODES 4096
#define BM 128
#define BN 128
#define BK 32
#define NSLICE (DIM / BK)      // 8
#define NCHUNK (KCODES / BN)   // 32

// d_ws layout (bytes): csq[4096]f32 | xsq[65536]f32 | ch[1M]f16 | cl[1M]f16  = 4.27 MB
#define WS_CSQ 0
#define WS_XSQ 16384
#define WS_CH  278528
#define WS_CL  2375680

// async global->LDS, 16B per lane, LDS dst = uniform base + lane*16
#define GLDS(g, l) __builtin_amdgcn_global_load_lds(                       \
    (const __attribute__((address_space(1))) unsigned int*)(g),            \
    (__attribute__((address_space(3))) unsigned int*)(l), 16, 0, 0)

// ---- Prologue 1: csq (k-ascending fmaf chain) + cb -> f16 hi/lo planes (x64) ----
__global__ void prep_codes(const float* __restrict__ cb, float* __restrict__ csq,
                           _Float16* __restrict__ ch, _Float16* __restrict__ cl) {
    int c = blockIdx.x * blockDim.x + threadIdx.x;
    if (c >= KCODES) return;
    const float* row = cb + (size_t)c * DIM;
    float s = 0.f;
    for (int k = 0; k < DIM; k += 4) {
        float4 v = *(const float4*)&row[k];
        s = fmaf(v.x, v.x, s); s = fmaf(v.y, v.y, s);
        s = fmaf(v.z, v.z, s); s = fmaf(v.w, v.w, s);
        float sv[4] = {v.x * 64.f, v.y * 64.f, v.z * 64.f, v.w * 64.f};
        #pragma unroll
        for (int j = 0; j < 4; ++j) {
            _Float16 h = (_Float16)sv[j];
            ch[(size_t)c * DIM + k + j] = h;
            cl[(size_t)c * DIM + k + j] = (_Float16)(sv[j] - (float)h);
        }
    }
    csq[c] = s;
}

// ---- Prologue 2: xsq via fp64 (matched ref) + emit packed x f16 hi/lo planes into out_q ----
// out_q row r (1024B) := [ xh row r (512B) | xl row r (512B) ]  -- race-free scratch:
// only block r/BM reads it, and overwrites it (gather) after its last A-read.
__global__ void prep_xsq(const float* __restrict__ x, float* __restrict__ xsq,
                         char* __restrict__ xq) {
    __shared__ float  As[32 * DIM];
    __shared__ double dtmp[128];
    const int t = threadIdx.x;
    const int n0 = blockIdx.x * 32;
    #pragma unroll
    for (int i = 0; i < 8; ++i) {
        int r = 4 * i + (t >> 6), d4 = (t & 63) * 4;
        *(float4*)&As[r * DIM + d4] = *(const float4*)&x[(size_t)(n0 + r) * DIM + d4];
    }
    __syncthreads();
    // hi/lo split, identical formula to the old in-loop staging (bit-exact)
    {
        const int r = t >> 3;
        const int col8 = (t & 7) * 8;
        char* dst = xq + (((size_t)(n0 + r)) << 10) + (size_t)(col8 * 2);
        const float* src = &As[r * DIM + col8];
        #pragma unroll
        for (int i = 0; i < 4; ++i) {
            half8 hv, lv;
            #pragma unroll
            for (int j = 0; j < 8; ++j) {
                float v = src[i * 64 + j];
                _Float16 h = (_Float16)v;
                hv[j] = h;
                lv[j] = (_Float16)(v - (float)h);
            }
            *(half8*)(dst + i * 128) = hv;          // hi plane
            *(half8*)(dst + 512 + i * 128) = lv;    // lo plane
        }
    }
    if (t < 128) {
        int r = t >> 2, part = t & 3;
        const float* ap = &As[r * DIM + 64 * part];
        double s = 0.0;
        for (int k = 0; k < 64; ++k) { double v = (double)ap[k]; s = fma(v, v, s); }
        dtmp[t] = s;
    }
    __syncthreads();
    if (t < 32)
        xsq[n0 + t] = (float)((dtmp[4*t] + dtmp[4*t+1]) + (dtmp[4*t+2] + dtmp[4*t+3]));
}

// ---- Main: 3-split f16 MFMA GEMM + fused argmin ----
// T3-minimum pipeline: STAGE(next, glds) || ds_read+MFMA(cur) -> vmcnt(0) -> 1 barrier/slice.
// LDS granule swizzle (g ^ (row&3)) applied on the *global source* address; LDS stays linear.
__global__ __launch_bounds__(256, 2)
void vq_mfma(const float* __restrict__ cb,
             const float* __restrict__ csq, const float* __restrict__ xsq,
             const _Float16* __restrict__ ch, const _Float16* __restrict__ cl,
             float* out_q, float* __restrict__ out_idx) {
    __shared__ _Float16 AhS[2 * BM * BK], AlS[2 * BM * BK];   // 16KB each
    __shared__ _Float16 BhS[2 * BN * BK], BlS[2 * BN * BK];   // 64KB total

    const int t = threadIdx.x;
    const int lane = t & 63, wave = t >> 6;
    const int wy = wave >> 1, wx = wave & 1;
    const int m = lane & 15, q = lane >> 4;   // MFMA: A/B row = m, k-granule = q; C: row=4q+e, col=m
    const int n0 = blockIdx.x * BM;
    const int swz = (q ^ (m & 3)) * 8;        // frag-read granule offset (f16 units)

    // per-lane glds source addressing: lane -> (row = base+lane>>2, phys granule = lane&3)
    const int rq  = lane >> 2;
    const int gph = lane & 3;
    const int glogB = ((gph ^ (rq & 3)) << 4);  // pre-swizzled source granule, bytes
    const char* xqb = (const char*)out_q;       // packed x planes written by prep_xsq
    const char* aBase  = xqb + (((size_t)(n0 + wave * 32 + rq)) << 10) + glogB;
    const char* bBaseH = (const char*)ch + (((size_t)(wave * 32 + rq)) << 9) + glogB;
    const char* bBaseL = (const char*)cl + (((size_t)(wave * 32 + rq)) << 9) + glogB;

    // A: row stride 1024B, j=1 adds 16 rows (16384B), lo plane +512B
    // B: row stride 512B,  j=1 adds 16 rows (8192B), chunk adds 128*512B = 65536B
#define STAGE(ck2, sl2, nb) do {                                             \
    const char* a_  = aBase  + (size_t)((sl2) * 64);                         \
    const size_t bo_ = ((size_t)(ck2) << 16) + (size_t)((sl2) * 64);         \
    const char* bh_ = bBaseH + bo_;                                          \
    const char* bl_ = bBaseL + bo_;                                          \
    _Float16* Ah_ = AhS + (nb) * (BM * BK) + wave * (32 * BK);               \
    _Float16* Al_ = AlS + (nb) * (BM * BK) + wave * (32 * BK);               \
    _Float16* Bh_ = BhS + (nb) * (BN * BK) + wave * (32 * BK);               \
    _Float16* Bl_ = BlS + (nb) * (BN * BK) + wave * (32 * BK);               \
    GLDS(a_,           Ah_);                                                 \
    GLDS(a_ + 16384,   Ah_ + 16 * BK);                                       \
    GLDS(a_ + 512,     Al_);                                                 \
    GLDS(a_ + 16896,   Al_ + 16 * BK);                                       \
    GLDS(bh_,          Bh_);                                                 \
    GLDS(bh_ + 8192,   Bh_ + 16 * BK);                                       \
    GLDS(bl_,          Bl_);                                                 \
    GLDS(bl_ + 8192,   Bl_ + 16 * BK);                                       \
} while (0)

    // frag read offsets (f16 units), constant per thread
    int aoffs[4], boffs[4];
    #pragma unroll
    for (int tr = 0; tr < 4; ++tr) aoffs[tr] = (64 * wy + 16 * tr + m) * BK + swz;
    #pragma unroll
    for (int tc = 0; tc < 4; ++tc) boffs[tc] = (64 * wx + 16 * tc + m) * BK + swz;

    float xsq_r[16];
    #pragma unroll
    for (int s = 0; s < 16; ++s)
        xsq_r[s] = xsq[n0 + 64 * wy + 16 * (s >> 2) + 4 * q + (s & 3)];

    float best[16]; int bidx[16];
    #pragma unroll
    for (int s = 0; s < 16; ++s) { best[s] = FLT_MAX; bidx[s] = 0; }

    // prologue: fill buf 0 with (chunk0, slice0)
    STAGE(0, 0, 0);
    asm volatile("s_waitcnt vmcnt(0)" ::: "memory");
    __syncthreads();

    for (int chunk = 0; chunk < NCHUNK; ++chunk) {
        const int c0 = chunk * BN;
        float csq_c[4];
        #pragma unroll
        for (int tc = 0; tc < 4; ++tc) csq_c[tc] = csq[c0 + 64 * wx + 16 * tc + m];

        f32x4 acc[4][4];
        #pragma unroll
        for (int tr = 0; tr < 4; ++tr)
            #pragma unroll
            for (int tc = 0; tc < 4; ++tc) acc[tr][tc] = (f32x4){0.f, 0.f, 0.f, 0.f};

        #pragma unroll
        for (int sl = 0; sl < NSLICE; ++sl) {
            // issue next-slice staging first (async, overlaps this slice's compute)
            if (sl < NSLICE - 1) {
                STAGE(chunk, sl + 1, (sl + 1) & 1);
            } else if (chunk < NCHUNK - 1) {
                STAGE(chunk + 1, 0, 0);
            }
            const int cbuf = sl & 1;
            const _Float16* Ahr = AhS + cbuf * (BM * BK);
            const _Float16* Alr = AlS + cbuf * (BM * BK);
            const _Float16* Bhr = BhS + cbuf * (BN * BK);
            const _Float16* Blr = BlS + cbuf * (BN * BK);

            half8 aH[4], aL[4], bH[4], bL[4];
            #pragma unroll
            for (int tr = 0; tr < 4; ++tr) {
                aH[tr] = *(const half8*)&Ahr[aoffs[tr]];
                aL[tr] = *(const half8*)&Alr[aoffs[tr]];
            }
            #pragma unroll
            for (int tc = 0; tc < 4; ++tc) {
                bH[tc] = *(const half8*)&Bhr[boffs[tc]];
                bL[tc] = *(const half8*)&Blr[boffs[tc]];
            }
            // 3 product sweeps, reuse distance 16 for full MFMA ILP (order preserved for bit-exactness)
            #pragma unroll
            for (int tc = 0; tc < 4; ++tc)
                #pragma unroll
                for (int tr = 0; tr < 4; ++tr)
                    acc[tr][tc] = __builtin_amdgcn_mfma_f32_16x16x32_f16(aH[tr], bH[tc], acc[tr][tc], 0, 0, 0);
            #pragma unroll
            for (int tc = 0; tc < 4; ++tc)
                #pragma unroll
                for (int tr = 0; tr < 4; ++tr)
                    acc[tr][tc] = __builtin_amdgcn_mfma_f32_16x16x32_f16(aH[tr], bL[tc], acc[tr][tc], 0, 0, 0);
            #pragma unroll
            for (int tc = 0; tc < 4; ++tc)
                #pragma unroll
                for (int tr = 0; tr < 4; ++tr)
                    acc[tr][tc] = __builtin_amdgcn_mfma_f32_16x16x32_f16(aL[tr], bH[tc], acc[tr][tc], 0, 0, 0);

            if (sl == NSLICE - 1) {
                // chunk epilogue: dist + running argmin (overlaps outstanding glds)
                #pragma unroll
                for (int tc = 0; tc < 4; ++tc) {
                    int c = c0 + 64 * wx + 16 * tc + m;
                    #pragma unroll
                    for (int tr = 0; tr < 4; ++tr) {
                        #pragma unroll
                        for (int e = 0; e < 4; ++e) {
                            float dot = acc[tr][tc][e] * 0.015625f;     // exact /64
                            float d = fmaf(-2.f, dot, xsq_r[tr * 4 + e]) + csq_c[tc];
                            int s = tr * 4 + e;
                            if (d < best[s]) { best[s] = d; bidx[s] = c; }
                        }
                    }
                }
            }
            // single sync point per slice: staged data complete + visible
            asm volatile("s_waitcnt vmcnt(0)" ::: "memory");
            __syncthreads();
        }
    }

    // reduce across the 16 lanes of each quad-group (same physical rows)
    #pragma unroll
    for (int s = 0; s < 16; ++s) {
        float v = best[s]; int idx = bidx[s];
        #pragma unroll
        for (int off = 1; off < 16; off <<= 1) {
            float v2 = __shfl_xor(v, off);
            int   i2 = __shfl_xor(idx, off);
            if (v2 < v || (v2 == v && i2 < idx)) { v = v2; idx = i2; }
        }
        best[s] = v; bidx[s] = idx;
    }
    __syncthreads();                      // staging LDS free now
    float* rb = (float*)BhS;              // [row][wx] candidates
    int*   ri = (int*)BlS;
    {
        int s = m;                        // lane writes slot == lane&15 (bijective over rows)
        int row_local = 64 * wy + 16 * (s >> 2) + 4 * q + (s & 3);
        rb[row_local * 2 + wx] = best[s];
        ri[row_local * 2 + wx] = bidx[s];
    }
    __syncthreads();
    int* widx = (int*)AhS;
    if (t < BM) {
        float d0 = rb[t * 2], d1 = rb[t * 2 + 1];
        int   i0 = ri[t * 2], i1 = ri[t * 2 + 1];
        int w = (d1 < d0 || (d1 == d0 && i1 < i0)) ? i1 : i0;
        widx[t] = w;
        out_idx[n0 + t] = (float)w;
    }
    __syncthreads();
    // gather winners, coalesced float4 (overwrites this block's packed-x scratch — all A reads done)
    const int l4 = t & 63, rg = t >> 6;
    #pragma unroll 4
    for (int i = 0; i < 32; ++i) {
        int r = rg + 4 * i;
        *(float4*)&out_q[(size_t)(n0 + r) * DIM + l4 * 4] =
            *(const float4*)&cb[(size_t)widx[r] * DIM + l4 * 4];
    }
#undef STAGE
}

extern "C" void kernel_launch(void* const* d_in, const int* in_sizes, int n_in,
                              void* d_out, int out_size, void* d_ws, size_t ws_size,
                              hipStream_t stream) {
    const float* x  = (const float*)d_in[0];
    const float* cb = (const float*)d_in[1];
    float* out_q   = (float*)d_out;
    float* out_idx = (float*)d_out + (size_t)N_ROWS * DIM;

    float*    csq = (float*)((char*)d_ws + WS_CSQ);
    float*    xsq = (float*)((char*)d_ws + WS_XSQ);
    _Float16* ch  = (_Float16*)((char*)d_ws + WS_CH);
    _Float16* cl  = (_Float16*)((char*)d_ws + WS_CL);

    prep_codes<<<KCODES / 256, 256, 0, stream>>>(cb, csq, ch, cl);
    prep_xsq<<<N_ROWS / 32, 256, 0, stream>>>(x, xsq, (char*)out_q);
    vq_mfma<<<N_ROWS / BM, 256, 0, stream>>>(cb, csq, xsq, ch, cl, out_q, out_idx);
}

// Round 3
// 565.600 us; speedup vs baseline: 1.1416x; 1.1416x over previous
//
#include <hip/hip_runtime.h>
#include <cfloat>

typedef _Float16 half8 __attribute__((ext_vector_type(8)));
typedef float    f32x4 __attribute__((ext_vector_type(4)));

#define N_ROWS 65536
#define DIM    256
#define KCODES 4096
#define BM 128
#define BN 128
#define BK 32
#define NSLICE (DIM / BK)      // 8
#define NCHUNK (KCODES / BN)   // 32

// d_ws layout (bytes): csq[4096]f32 | (gap) | ch[1M]f16 | cl[1M]f16
#define WS_CSQ 0
#define WS_CH  278528
#define WS_CL  2375680

// async global->LDS, 16B per lane, LDS dst = uniform base + lane*16
#define GLDS(g, l) __builtin_amdgcn_global_load_lds(                       \
    (const __attribute__((address_space(1))) unsigned int*)(g),            \
    (__attribute__((address_space(3))) unsigned int*)(l), 16, 0, 0)

// ---- Prologue: csq (k-ascending fmaf chain, matches ref) + cb -> f16 hi/lo planes (x64) ----
// Coalesced via LDS staging.
__global__ void prep_codes(const float* __restrict__ cb, float* __restrict__ csq,
                           _Float16* __restrict__ ch, _Float16* __restrict__ cl) {
    __shared__ float As[32 * DIM];   // 32KB
    const int t = threadIdx.x;
    const int c0 = blockIdx.x * 32;
    #pragma unroll
    for (int i = 0; i < 8; ++i) {
        int r = 4 * i + (t >> 6), d4 = (t & 63) * 4;
        *(float4*)&As[r * DIM + d4] = *(const float4*)&cb[(size_t)(c0 + r) * DIM + d4];
    }
    __syncthreads();
    // pack: 8 threads/row, 32 cols each; hi=(f16)(v*64), lo=(f16)(v*64-hi)  (identical formula)
    {
        const int r = t >> 3;
        const int k0 = (t & 7) * 32;
        const float* src = &As[r * DIM + k0];
        _Float16* dh = &ch[(size_t)(c0 + r) * DIM + k0];
        _Float16* dl = &cl[(size_t)(c0 + r) * DIM + k0];
        #pragma unroll
        for (int i = 0; i < 4; ++i) {
            half8 hv, lv;
            #pragma unroll
            for (int j = 0; j < 8; ++j) {
                float sv = src[i * 8 + j] * 64.f;
                _Float16 h = (_Float16)sv;
                hv[j] = h; lv[j] = (_Float16)(sv - (float)h);
            }
            *(half8*)(dh + i * 8) = hv;
            *(half8*)(dl + i * 8) = lv;
        }
    }
    if (t < 32) {
        const float* row = &As[t * DIM];
        float s = 0.f;
        for (int k = 0; k < DIM; ++k) s = fmaf(row[k], row[k], s);   // k-ascending chain
        csq[c0 + t] = s;
    }
}

// ---- Main: fused x-prep + 3-split f16 MFMA GEMM + fused argmin ----
// Pipeline: 2-slice-ahead prefetch on 2 LDS buffers, counted vmcnt(8) (never drains to 0
// in steady state). Per slice: ds_read frags -> lgkmcnt(0)+barrier -> STAGE(sl+2) into the
// buffer just read -> MFMA -> vmcnt(8)+barrier.
__global__ __launch_bounds__(256, 2)
void vq_mfma(const float* __restrict__ x, const float* __restrict__ cb,
             const float* __restrict__ csq,
             const _Float16* __restrict__ ch, const _Float16* __restrict__ cl,
             float* out_q, float* __restrict__ out_idx) {
    __shared__ _Float16 LDS[8 * BM * BK];          // 64KB total
    _Float16* AhS = LDS;                           // [2][BM][BK]
    _Float16* AlS = LDS + 2 * BM * BK;
    _Float16* BhS = LDS + 4 * BM * BK;
    _Float16* BlS = LDS + 6 * BM * BK;

    const int t = threadIdx.x;
    const int lane = t & 63, wave = t >> 6;
    const int wy = wave >> 1, wx = wave & 1;
    const int m = lane & 15, q = lane >> 4;   // MFMA: A/B row = m, k-granule = q; C: row=4q+e, col=m
    const int n0 = blockIdx.x * BM;
    const int swz = (q ^ (m & 3)) * 8;        // frag-read granule offset (f16 units)

    // ======== fused x-prep: 4 groups of 32 rows ========
    // planes -> out_q scratch rows n0..n0+127 (1KB/row: [hi 512B | lo 512B]), xsq -> LDS
    {
        float*  prepF = (float*)LDS;                   // 32KB: 32 rows x 256 f32 (AhS+AlS)
        double* dtmp  = (double*)(LDS + 4 * BM * BK);  // 1KB (BhS region)
        float*  xsqS  = (float*)(LDS + 6 * BM * BK);   // 512B (BlS region)
        char*   xqw   = (char*)out_q;
        for (int g = 0; g < 4; ++g) {
            const int r0 = g * 32;
            #pragma unroll
            for (int i = 0; i < 8; ++i) {
                int r = 4 * i + (t >> 6), d4 = (t & 63) * 4;
                *(float4*)&prepF[r * DIM + d4] =
                    *(const float4*)&x[(size_t)(n0 + r0 + r) * DIM + d4];
            }
            __syncthreads();
            // hi/lo pack (unscaled A, identical formula to prior rounds)
            {
                const int r = t >> 3;
                const int col8 = (t & 7) * 8;
                char* dst = xqw + (((size_t)(n0 + r0 + r)) << 10) + (size_t)(col8 * 2);
                const float* src = &prepF[r * DIM + col8];
                #pragma unroll
                for (int i = 0; i < 4; ++i) {
                    half8 hv, lv;
                    #pragma unroll
                    for (int j = 0; j < 8; ++j) {
                        float v = src[i * 64 + j];
                        _Float16 h = (_Float16)v;
                        hv[j] = h; lv[j] = (_Float16)(v - (float)h);
                    }
                    *(half8*)(dst + i * 128) = hv;          // hi plane
                    *(half8*)(dst + 512 + i * 128) = lv;    // lo plane
                }
            }
            // xsq via fp64, identical association: 4 partials of 64, (p0+p1)+(p2+p3)
            if (t < 128) {
                int r = t >> 2, part = t & 3;
                const float* ap = &prepF[r * DIM + 64 * part];
                double s = 0.0;
                for (int k = 0; k < 64; ++k) { double v = (double)ap[k]; s = fma(v, v, s); }
                dtmp[t] = s;
            }
            __syncthreads();
            if (t < 32)
                xsqS[r0 + t] = (float)((dtmp[4*t] + dtmp[4*t+1]) + (dtmp[4*t+2] + dtmp[4*t+3]));
            __syncthreads();
        }
    }

    float xsq_r[16];
    {
        const float* xsqS = (const float*)(LDS + 6 * BM * BK);
        #pragma unroll
        for (int s = 0; s < 16; ++s)
            xsq_r[s] = xsqS[64 * wy + 16 * (s >> 2) + 4 * q + (s & 3)];
    }
    // plane stores must be visible before glds reads them back
    asm volatile("s_waitcnt vmcnt(0)" ::: "memory");
    __syncthreads();

    // ======== staging addressing (round-1 verified) ========
    const int rq  = lane >> 2;
    const int gph = lane & 3;
    const int glogB = ((gph ^ (rq & 3)) << 4);  // pre-swizzled source granule, bytes
    const char* xqb = (const char*)out_q;
    const char* aBase  = xqb + (((size_t)(n0 + wave * 32 + rq)) << 10) + glogB;
    const char* bBaseH = (const char*)ch + (((size_t)(wave * 32 + rq)) << 9) + glogB;
    const char* bBaseL = (const char*)cl + (((size_t)(wave * 32 + rq)) << 9) + glogB;

#define STAGE(ck2, sl2, nb) do {                                             \
    const char* a_  = aBase  + (size_t)((sl2) * 64);                         \
    const size_t bo_ = ((size_t)(ck2) << 16) + (size_t)((sl2) * 64);         \
    const char* bh_ = bBaseH + bo_;                                          \
    const char* bl_ = bBaseL + bo_;                                          \
    _Float16* Ah_ = AhS + (nb) * (BM * BK) + wave * (32 * BK);               \
    _Float16* Al_ = AlS + (nb) * (BM * BK) + wave * (32 * BK);               \
    _Float16* Bh_ = BhS + (nb) * (BN * BK) + wave * (32 * BK);               \
    _Float16* Bl_ = BlS + (nb) * (BN * BK) + wave * (32 * BK);               \
    GLDS(a_,           Ah_);                                                 \
    GLDS(a_ + 16384,   Ah_ + 16 * BK);                                       \
    GLDS(a_ + 512,     Al_);                                                 \
    GLDS(a_ + 16896,   Al_ + 16 * BK);                                       \
    GLDS(bh_,          Bh_);                                                 \
    GLDS(bh_ + 8192,   Bh_ + 16 * BK);                                       \
    GLDS(bl_,          Bl_);                                                 \
    GLDS(bl_ + 8192,   Bl_ + 16 * BK);                                       \
} while (0)

    int aoffs[4], boffs[4];
    #pragma unroll
    for (int tr = 0; tr < 4; ++tr) aoffs[tr] = (64 * wy + 16 * tr + m) * BK + swz;
    #pragma unroll
    for (int tc = 0; tc < 4; ++tc) boffs[tc] = (64 * wx + 16 * tc + m) * BK + swz;

    float best[16]; int bidx[16];
    #pragma unroll
    for (int s = 0; s < 16; ++s) { best[s] = FLT_MAX; bidx[s] = 0; }

    // pipeline prologue: slices 0 and 1 in flight; require slice 0 complete
    STAGE(0, 0, 0);
    STAGE(0, 1, 1);
    asm volatile("s_waitcnt vmcnt(8)" ::: "memory");
    __builtin_amdgcn_s_barrier();
    __builtin_amdgcn_sched_barrier(0);

    for (int chunk = 0; chunk < NCHUNK; ++chunk) {
        const int c0 = chunk * BN;
        float csq_c[4];
        #pragma unroll
        for (int tc = 0; tc < 4; ++tc) csq_c[tc] = csq[c0 + 64 * wx + 16 * tc + m];

        f32x4 acc[4][4];
        #pragma unroll
        for (int tr = 0; tr < 4; ++tr)
            #pragma unroll
            for (int tc = 0; tc < 4; ++tc) acc[tr][tc] = (f32x4){0.f, 0.f, 0.f, 0.f};

        #pragma unroll
        for (int sl = 0; sl < NSLICE; ++sl) {
            const int cbuf = sl & 1;
            const _Float16* Ahr = AhS + cbuf * (BM * BK);
            const _Float16* Alr = AlS + cbuf * (BM * BK);
            const _Float16* Bhr = BhS + cbuf * (BN * BK);
            const _Float16* Blr = BlS + cbuf * (BN * BK);

            half8 aH[4], aL[4], bH[4], bL[4];
            #pragma unroll
            for (int tr = 0; tr < 4; ++tr) {
                aH[tr] = *(const half8*)&Ahr[aoffs[tr]];
                aL[tr] = *(const half8*)&Alr[aoffs[tr]];
            }
            #pragma unroll
            for (int tc = 0; tc < 4; ++tc) {
                bH[tc] = *(const half8*)&Bhr[boffs[tc]];
                bL[tc] = *(const half8*)&Blr[boffs[tc]];
            }

            // prefetch slice sl+2 into the buffer we just finished reading
            const int sl2r = sl + 2;
            const int ck2 = chunk + (sl2r >> 3);
            const int sl2 = sl2r & 7;
            const bool stg = (ck2 < NCHUNK);
            if (stg) {
                asm volatile("s_waitcnt lgkmcnt(0)" ::: "memory");  // frags in regs
                __builtin_amdgcn_s_barrier();                        // all waves done reading
                __builtin_amdgcn_sched_barrier(0);
                STAGE(ck2, sl2, cbuf);
            }

            // 3 product sweeps, reuse distance 16 for full MFMA ILP (order = bit-exact)
            #pragma unroll
            for (int tc = 0; tc < 4; ++tc)
                #pragma unroll
                for (int tr = 0; tr < 4; ++tr)
                    acc[tr][tc] = __builtin_amdgcn_mfma_f32_16x16x32_f16(aH[tr], bH[tc], acc[tr][tc], 0, 0, 0);
            #pragma unroll
            for (int tc = 0; tc < 4; ++tc)
                #pragma unroll
                for (int tr = 0; tr < 4; ++tr)
                    acc[tr][tc] = __builtin_amdgcn_mfma_f32_16x16x32_f16(aH[tr], bL[tc], acc[tr][tc], 0, 0, 0);
            #pragma unroll
            for (int tc = 0; tc < 4; ++tc)
                #pragma unroll
                for (int tr = 0; tr < 4; ++tr)
                    acc[tr][tc] = __builtin_amdgcn_mfma_f32_16x16x32_f16(aL[tr], bH[tc], acc[tr][tc], 0, 0, 0);

            if (sl == NSLICE - 1) {
                // chunk epilogue: dist + running argmin (cols ascend)
                #pragma unroll
                for (int tc = 0; tc < 4; ++tc) {
                    int c = c0 + 64 * wx + 16 * tc + m;
                    #pragma unroll
                    for (int tr = 0; tr < 4; ++tr) {
                        #pragma unroll
                        for (int e = 0; e < 4; ++e) {
                            float dot = acc[tr][tc][e] * 0.015625f;     // exact /64
                            float d = fmaf(-2.f, dot, xsq_r[tr * 4 + e]) + csq_c[tc];
                            int s = tr * 4 + e;
                            if (d < best[s]) { best[s] = d; bidx[s] = c; }
                        }
                    }
                }
            }

            if (!(chunk == NCHUNK - 1 && sl == NSLICE - 1)) {
                // counted wait: STAGE(sl+1) (issued a full slice ago) must be done;
                // STAGE(sl+2)'s 8 loads stay in flight.
                if (stg) asm volatile("s_waitcnt vmcnt(8)" ::: "memory");
                else     asm volatile("s_waitcnt vmcnt(0)" ::: "memory");
                __builtin_amdgcn_s_barrier();
                __builtin_amdgcn_sched_barrier(0);
            }
        }
    }

    // reduce across the 16 lanes of each quad-group (same physical rows)
    #pragma unroll
    for (int s = 0; s < 16; ++s) {
        float v = best[s]; int idx = bidx[s];
        #pragma unroll
        for (int off = 1; off < 16; off <<= 1) {
            float v2 = __shfl_xor(v, off);
            int   i2 = __shfl_xor(idx, off);
            if (v2 < v || (v2 == v && i2 < idx)) { v = v2; idx = i2; }
        }
        best[s] = v; bidx[s] = idx;
    }
    __syncthreads();                      // staging LDS free now
    float* rb = (float*)BhS;              // [row][wx] candidates
    int*   ri = (int*)BlS;
    {
        int s = m;                        // lane writes slot == lane&15 (bijective over rows)
        int row_local = 64 * wy + 16 * (s >> 2) + 4 * q + (s & 3);
        rb[row_local * 2 + wx] = best[s];
        ri[row_local * 2 + wx] = bidx[s];
    }
    __syncthreads();
    int* widx = (int*)AhS;
    if (t < BM) {
        float d0 = rb[t * 2], d1 = rb[t * 2 + 1];
        int   i0 = ri[t * 2], i1 = ri[t * 2 + 1];
        int w = (d1 < d0 || (d1 == d0 && i1 < i0)) ? i1 : i0;
        widx[t] = w;
        out_idx[n0 + t] = (float)w;
    }
    __syncthreads();
    // gather winners, coalesced float4 (overwrites this block's packed-x scratch — all A reads done)
    const int l4 = t & 63, rg = t >> 6;
    #pragma unroll 4
    for (int i = 0; i < 32; ++i) {
        int r = rg + 4 * i;
        *(float4*)&out_q[(size_t)(n0 + r) * DIM + l4 * 4] =
            *(const float4*)&cb[(size_t)widx[r] * DIM + l4 * 4];
    }
#undef STAGE
}

extern "C" void kernel_launch(void* const* d_in, const int* in_sizes, int n_in,
                              void* d_out, int out_size, void* d_ws, size_t ws_size,
                              hipStream_t stream) {
    const float* x  = (const float*)d_in[0];
    const float* cb = (const float*)d_in[1];
    float* out_q   = (float*)d_out;
    float* out_idx = (float*)d_out + (size_t)N_ROWS * DIM;

    float*    csq = (float*)((char*)d_ws + WS_CSQ);
    _Float16* ch  = (_Float16*)((char*)d_ws + WS_CH);
    _Float16* cl  = (_Float16*)((char*)d_ws + WS_CL);

    prep_codes<<<KCODES / 32, 256, 0, stream>>>(cb, csq, ch, cl);
    vq_mfma<<<N_ROWS / BM, 256, 0, stream>>>(x, cb, csq, ch, cl, out_q, out_idx);
}